// Round 5
// baseline (634.547 us; speedup 1.0000x reference)
//
#include <hip/hip_runtime.h>
#include <hip/hip_bf16.h>
#include <stdint.h>

#define L_ 25
#define E_ 64
#define H_ 8
#define B_ 1000
#define S_ 512
#define GQ 4                       // batch elements per block
#define NCELL (L_ * GQ)            // 100 cells per block
#define TPBR (NCELL * 8)           // 800 threads, thread = (cell, j)
#define NSUPER (S_ / 2 + L_ - 1)   // 280 supersteps (2 timesteps each)
#define XG 20                      // per-cell stride xbuf (words): b128 reads bank-disjoint

// pin 8/3 floats into VGPRs; executed in-loop so the compiler cannot remat
#define PIN8(a) asm volatile("" : "+v"(a[0]), "+v"(a[1]), "+v"(a[2]), "+v"(a[3]), \
                                  "+v"(a[4]), "+v"(a[5]), "+v"(a[6]), "+v"(a[7]))
#define PIN3(a, b, c) asm volatile("" : "+v"(a), "+v"(b), "+v"(c))

__device__ __forceinline__ float ulo(uint32_t u) { return __uint_as_float(u << 16); }
__device__ __forceinline__ float uhi(uint32_t u) { return __uint_as_float(u & 0xffff0000u); }

__device__ __forceinline__ float toF(float v) { return v; }
__device__ __forceinline__ float toF(__hip_bfloat16 v) { return __bfloat162float(v); }
__device__ __forceinline__ void stP(float* p, float v) { *p = v; }
__device__ __forceinline__ void stP(__hip_bfloat16* p, float v) { *p = __float2bfloat16(v); }

__device__ __forceinline__ void load8f(const __hip_bfloat16* p, float* o) {
  const uint4 v = *(const uint4*)p;
  o[0] = ulo(v.x); o[1] = uhi(v.x); o[2] = ulo(v.y); o[3] = uhi(v.y);
  o[4] = ulo(v.z); o[5] = uhi(v.z); o[6] = ulo(v.w); o[7] = uhi(v.w);
}
__device__ __forceinline__ void load8f(const float* p, float* o) {
  const float4 a = ((const float4*)p)[0];
  const float4 b = ((const float4*)p)[1];
  o[0] = a.x; o[1] = a.y; o[2] = a.z; o[3] = a.w;
  o[4] = b.x; o[5] = b.y; o[6] = b.z; o[7] = b.w;
}

__device__ __forceinline__ float sigmo(float x) {
  x = fminf(fmaxf(x, -30.f), 30.f);
  return 1.f / (1.f + __expf(-x));
}
__device__ __forceinline__ float tanh_(float x) {
  x = fminf(fmaxf(x, -15.f), 15.f);
  const float e = __expf(-2.f * x);
  return (1.f - e) / (1.f + e);
}

// ---- cross-lane XOR exchange within 8-lane cells ----
template <int CTRL>
__device__ __forceinline__ float qp(float v) {  // quad_perm / row ops (VALU DPP)
  return __int_as_float(__builtin_amdgcn_mov_dpp(__float_as_int(v), CTRL, 0xF, 0xF, true));
}
__device__ __forceinline__ float swz4(float v) {  // lane ^= 4 (DS pipe)
  return __int_as_float(__builtin_amdgcn_ds_swizzle(__float_as_int(v), 0x101F));
}
// o[k] = value of (lane ^ k) within the 8-lane group
__device__ __forceinline__ void tour8(float v, float* o) {
  o[0] = v;
  o[1] = qp<0xB1>(v);   // ^1: quad_perm [1,0,3,2]
  o[2] = qp<0x4E>(v);   // ^2: quad_perm [2,3,0,1]
  o[3] = qp<0x1B>(v);   // ^3: quad_perm [3,2,1,0]
  const float v4 = swz4(v);
  o[4] = v4;
  o[5] = qp<0xB1>(v4);  // ^5
  o[6] = qp<0x4E>(v4);  // ^6
  o[7] = qp<0x1B>(v4);  // ^7
}

// one GRU cell update; whz/whr/wrh are XOR-permuted columns: w[k] = W[(j^k)][j]
__device__ __forceinline__ float cellstep(float hown, float az, float ar, float ah,
                                          const float* whz, const float* whr,
                                          const float* wrh) {
  float hv[8];
  tour8(hown, hv);
#pragma unroll
  for (int k = 0; k < 8; ++k) {
    az = fmaf(hv[k], whz[k], az);
    ar = fmaf(hv[k], whr[k], ar);
  }
  const float z = sigmo(az);
  const float r = sigmo(ar);
  float hrv[8];
  tour8(hown * r, hrv);
#pragma unroll
  for (int k = 0; k < 8; ++k) ah = fmaf(hrv[k], wrh[k], ah);
  return fmaf(z, tanh_(ah) - hown, hown);
}

// ---------------------------------------------------------------------------
// Kernel 0: dtype probe (fp32 vs bf16 inputs).
// ---------------------------------------------------------------------------
__global__ void gru_detect(const unsigned short* __restrict__ u16, int* __restrict__ flag) {
  const int i = threadIdx.x;  // 64 threads
  float m = 0.f;
#pragma unroll
  for (int k = 0; k < 4; ++k) {
    const uint32_t u = u16[i * 4 + k];
    float v = fabsf(__uint_as_float(u << 16));
    if (!(v < 1e30f)) v = 1e30f;
    m = fmaxf(m, v);
  }
#pragma unroll
  for (int off = 32; off; off >>= 1) m = fmaxf(m, __shfl_down(m, off, 64));
  if (i == 0) *flag = (m > 2.0f) ? 0 : 1;  // 0 = fp32 inputs, 1 = bf16 inputs
}

// ---------------------------------------------------------------------------
// Kernel 1: layer-0 x-projections, weights staged in LDS (broadcast reads).
// pre[(b*S+t)*24 + gate*8 + j]. Thread = 2 tokens; 1000 blocks x 256.
// ---------------------------------------------------------------------------
template <typename T, typename PT>
__global__ __launch_bounds__(256, 4) void gru_pre(
    const int* __restrict__ flag, int want,
    const int* __restrict__ x, const T* __restrict__ emb,
    const T* __restrict__ Wz, const T* __restrict__ Wr,
    const T* __restrict__ Wh, PT* __restrict__ pre) {
  if (*flag != want) return;
  __shared__ __align__(16) float WL[64 * 24];  // [k][z8 r8 h8], 6 KB
  for (int idx = threadIdx.x; idx < 64 * 24; idx += 256) {
    const int k = idx / 24, c = idx - k * 24;
    const T* src = (c < 8) ? Wz : ((c < 16) ? Wr : Wh);
    WL[idx] = toF(src[k * 8 + (c & 7)]);
  }
  __syncthreads();

  const int pos0 = (blockIdx.x * 256 + threadIdx.x) * 2;  // 2 tokens/thread
  const int2 t2 = *(const int2*)(x + pos0);

  float acc[2][24];
#pragma unroll
  for (int p = 0; p < 2; ++p)
#pragma unroll
    for (int c = 0; c < 24; ++c) acc[p][c] = 0.f;

  for (int kb = 0; kb < 8; ++kb) {
    float e0[8], e1[8];
    load8f(emb + (size_t)t2.x * E_ + kb * 8, e0);
    load8f(emb + (size_t)t2.y * E_ + kb * 8, e1);
#pragma unroll
    for (int k8 = 0; k8 < 8; ++k8) {
      const float* wr = WL + (kb * 8 + k8) * 24;
      float wf[24];
#pragma unroll
      for (int q = 0; q < 6; ++q) {
        const float4 w4 = ((const float4*)wr)[q];
        wf[4 * q] = w4.x; wf[4 * q + 1] = w4.y; wf[4 * q + 2] = w4.z; wf[4 * q + 3] = w4.w;
      }
#pragma unroll
      for (int c = 0; c < 24; ++c) {
        acc[0][c] = fmaf(e0[k8], wf[c], acc[0][c]);
        acc[1][c] = fmaf(e1[k8], wf[c], acc[1][c]);
      }
    }
  }
#pragma unroll
  for (int p = 0; p < 2; ++p) {
    PT* o = pre + (size_t)(pos0 + p) * 24;
#pragma unroll
    for (int c = 0; c < 24; ++c) stP(o + c, acc[p][c]);
  }
}

// ---------------------------------------------------------------------------
// Kernel 2: pipelined recurrence. Superstep s: layer l does t = 2(s-l), +1.
// h / h*r shared via DPP+swizzle XOR tours (no LDS). Only the inter-layer x
// handoff uses LDS (double-buffered xbuf). Weights pinned in VGPRs in-loop.
// ---------------------------------------------------------------------------
template <typename T, typename PT>
__global__ __launch_bounds__(TPBR, 4) void gru_rec(
    const int* __restrict__ flag, int want,
    const PT* __restrict__ pre,
    const T* __restrict__ Whz0, const T* __restrict__ bz0,
    const T* __restrict__ Whr0, const T* __restrict__ br0,
    const T* __restrict__ WrH0, const T* __restrict__ bH0,
    const T* __restrict__ Wxz, const T* __restrict__ Whz,
    const T* __restrict__ bz, const T* __restrict__ Wxr,
    const T* __restrict__ Whr, const T* __restrict__ br,
    const T* __restrict__ WxH, const T* __restrict__ WrH,
    const T* __restrict__ bH, const T* __restrict__ Why,
    const T* __restrict__ by, T* __restrict__ out) {
  if (*flag != want) return;
  __shared__ __align__(16) float xbuf[2 * NCELL * XG];

  const int tid = threadIdx.x;
  const int gi = tid >> 3;   // cell = l*GQ + g, 0..99
  const int j = tid & 7;
  const int l = gi >> 2;
  const int g = gi & 3;
  const int b = blockIdx.x * GQ + g;

  // ---- weights into registers. wh*/wrh use XOR-permuted rows: w[k]=W[(j^k)][j]
  float wxz[8], whz[8], wxr[8], whr[8], wxh[8], wrh[8];
  float vbz, vbr, vbh;
  if (l == 0) {
#pragma unroll
    for (int k = 0; k < 8; ++k) {
      const int rk = (j ^ k) * 8 + j;
      whz[k] = toF(Whz0[rk]);
      whr[k] = toF(Whr0[rk]);
      wrh[k] = toF(WrH0[rk]);
      wxz[k] = 0.f; wxr[k] = 0.f; wxh[k] = 0.f;
    }
    vbz = toF(bz0[j]); vbr = toF(br0[j]); vbh = toF(bH0[j]);
  } else {
    const int base = (l - 1) * 64;
#pragma unroll
    for (int k = 0; k < 8; ++k) {
      const int nk = base + k * 8 + j;        // natural order (x is per-lane complete)
      const int rk = base + (j ^ k) * 8 + j;  // xor order (h is toured)
      wxz[k] = toF(Wxz[nk]);
      wxr[k] = toF(Wxr[nk]);
      wxh[k] = toF(WxH[nk]);
      whz[k] = toF(Whz[rk]);
      whr[k] = toF(Whr[rk]);
      wrh[k] = toF(WrH[rk]);
    }
    vbz = toF(bz[(l - 1) * 8 + j]);
    vbr = toF(br[(l - 1) * 8 + j]);
    vbh = toF(bH[(l - 1) * 8 + j]);
  }

  // layer-0 precomputed x-projection (register prefetch)
  const PT* ppr = pre + (size_t)b * (S_ * 24) + j;
  float cz0 = 0.f, cr0 = 0.f, ch0 = 0.f, cz1 = 0.f, cr1 = 0.f, ch1 = 0.f;
  if (l == 0) {
    cz0 = toF(ppr[0]);  cr0 = toF(ppr[8]);  ch0 = toF(ppr[16]);
    cz1 = toF(ppr[24]); cr1 = toF(ppr[32]); ch1 = toF(ppr[40]);
  }

  const int gp = (gi >= GQ) ? (gi - GQ) * XG : 0;
  const float* xpe = xbuf + NCELL * XG + gp;  // read when s even
  const float* xpo = xbuf + gp;               // read when s odd
  float* xce = xbuf + gi * XG;                // write when s even
  float* xco = xbuf + NCELL * XG + gi * XG;   // write when s odd

  float hown = 0.f;  // this thread's h[j], carried across supersteps

  __syncthreads();

  for (int s = 0; s < NSUPER; ++s) {
    // force weights to stay live in VGPRs (no remat) — emits no instructions
    PIN8(wxz); PIN8(whz); PIN8(wxr); PIN8(whr); PIN8(wxh); PIN8(wrh);
    PIN3(vbz, vbr, vbh);

    const unsigned rel = (unsigned)(s - l);
    if (rel < (unsigned)(S_ / 2)) {
      const float* xp = (s & 1) ? xpo : xpe;
      float* xc = (s & 1) ? xco : xce;

      // ---- x-contributions for both timeslots ----
      float az0, ar0, ah0, az1, ar1, ah1;
      if (l == 0) {
        az0 = vbz + cz0; ar0 = vbr + cr0; ah0 = vbh + ch0;
        az1 = vbz + cz1; ar1 = vbr + cr1; ah1 = vbh + ch1;
        if (rel + 1 < (unsigned)(S_ / 2)) {  // prefetch next superstep
          const PT* pn = ppr + (rel + 1) * 48;
          cz0 = toF(pn[0]);  cr0 = toF(pn[8]);  ch0 = toF(pn[16]);
          cz1 = toF(pn[24]); cr1 = toF(pn[32]); ch1 = toF(pn[40]);
        }
      } else {
        float xv0[8], xv1[8];
        {
          const float4 a0 = ((const float4*)xp)[0];
          const float4 b0 = ((const float4*)xp)[1];
          const float4 a1 = ((const float4*)xp)[2];
          const float4 b1 = ((const float4*)xp)[3];
          xv0[0] = a0.x; xv0[1] = a0.y; xv0[2] = a0.z; xv0[3] = a0.w;
          xv0[4] = b0.x; xv0[5] = b0.y; xv0[6] = b0.z; xv0[7] = b0.w;
          xv1[0] = a1.x; xv1[1] = a1.y; xv1[2] = a1.z; xv1[3] = a1.w;
          xv1[4] = b1.x; xv1[5] = b1.y; xv1[6] = b1.z; xv1[7] = b1.w;
        }
        az0 = vbz; ar0 = vbr; ah0 = vbh;
        az1 = vbz; ar1 = vbr; ah1 = vbh;
#pragma unroll
        for (int k = 0; k < 8; ++k) {
          az0 = fmaf(xv0[k], wxz[k], az0);
          ar0 = fmaf(xv0[k], wxr[k], ar0);
          ah0 = fmaf(xv0[k], wxh[k], ah0);
          az1 = fmaf(xv1[k], wxz[k], az1);
          ar1 = fmaf(xv1[k], wxr[k], ar1);
          ah1 = fmaf(xv1[k], wxh[k], ah1);
        }
      }

      // ---- two sequential cell updates, all cross-lane via tours ----
      const float hn0 = cellstep(hown, az0, ar0, ah0, whz, whr, wrh);
      xc[j] = hn0;
      const float hn1 = cellstep(hn0, az1, ar1, ah1, whz, whr, wrh);
      xc[8 + j] = hn1;
      hown = hn1;
    }
    __syncthreads();
  }

  // ---- epilogue: h_last and logits (lane-reduced, no LDS) ----
  stP(out + B_ + (l * B_ + b) * H_ + j, hown);
  if (l == L_ - 1) {
    float sum = hown * toF(Why[j]);
    sum += qp<0xB1>(sum);   // ^1
    sum += qp<0x4E>(sum);   // ^2
    sum += swz4(sum);       // ^4
    if (j == 0) stP(out + b, sum + toF(by[0]));
  }
}

// ---------------------------------------------------------------------------
template <typename T, typename PT>
static void launch_mode(const int* flag, int want, void* const* d_in, PT* pre,
                        T* out, hipStream_t stream) {
  const int* x = (const int*)d_in[0];
  const T* emb = (const T*)d_in[1];
  const T* Wxz0 = (const T*)d_in[2];
  const T* Whz0 = (const T*)d_in[3];
  const T* bz0 = (const T*)d_in[4];
  const T* Wxr0 = (const T*)d_in[5];
  const T* Whr0 = (const T*)d_in[6];
  const T* br0 = (const T*)d_in[7];
  const T* WxH0 = (const T*)d_in[8];
  const T* WrH0 = (const T*)d_in[9];
  const T* bH0 = (const T*)d_in[10];
  const T* Wxz = (const T*)d_in[11];
  const T* Whz = (const T*)d_in[12];
  const T* bz = (const T*)d_in[13];
  const T* Wxr = (const T*)d_in[14];
  const T* Whr = (const T*)d_in[15];
  const T* br = (const T*)d_in[16];
  const T* WxH = (const T*)d_in[17];
  const T* WrH = (const T*)d_in[18];
  const T* bH = (const T*)d_in[19];
  const T* Why = (const T*)d_in[20];
  const T* by = (const T*)d_in[21];

  gru_pre<T, PT><<<B_ * S_ / 2 / 256, 256, 0, stream>>>(flag, want, x, emb,
                                                        Wxz0, Wxr0, WxH0, pre);
  gru_rec<T, PT><<<B_ / GQ, TPBR, 0, stream>>>(
      flag, want, pre, Whz0, bz0, Whr0, br0, WrH0, bH0, Wxz, Whz, bz, Wxr, Whr,
      br, WxH, WrH, bH, Why, by, out);
}

extern "C" void kernel_launch(void* const* d_in, const int* in_sizes, int n_in,
                              void* d_out, int out_size, void* d_ws, size_t ws_size,
                              hipStream_t stream) {
  int* flag = (int*)d_ws;
  char* preMem = (char*)d_ws + 256;
  const size_t needF = (size_t)B_ * S_ * 24 * sizeof(float) + 256;

  gru_detect<<<1, 64, 0, stream>>>((const unsigned short*)d_in[1], flag);

  if (ws_size >= needF) {
    float* pre = (float*)preMem;
    launch_mode<float, float>(flag, 0, d_in, pre, (float*)d_out, stream);
    launch_mode<__hip_bfloat16, float>(flag, 1, d_in, pre, (__hip_bfloat16*)d_out, stream);
  } else {
    __hip_bfloat16* pre = (__hip_bfloat16*)preMem;
    launch_mode<float, __hip_bfloat16>(flag, 0, d_in, pre, (float*)d_out, stream);
    launch_mode<__hip_bfloat16, __hip_bfloat16>(flag, 1, d_in, pre, (__hip_bfloat16*)d_out, stream);
  }
}